// Round 1
// baseline (354.161 us; speedup 1.0000x reference)
//
#include <hip/hip_runtime.h>

#define BATCH   4096
#define SLOTS   26
#define MAX_NNZ 10
#define EMB     64
#define ROWS    (BATCH * SLOTS)   // 106,496 output rows

// One output row [EMB=64 floats] is handled by 16 lanes, each owning one
// float4. A 64-lane wave therefore processes 4 rows concurrently.
__global__ __launch_bounds__(256) void emb_fwd_kernel(
    const int*   __restrict__ keys,   // [ROWS, MAX_NNZ]
    const int*   __restrict__ mask,   // [ROWS, MAX_NNZ] (0/1)
    const float* __restrict__ table,  // [VOCAB, EMB]
    float*       __restrict__ out)    // [ROWS, EMB]
{
    int tid = blockIdx.x * blockDim.x + threadIdx.x;
    int row = tid >> 4;        // 16 lanes per row
    int e4  = tid & 15;        // which float4 of the 64-float row
    if (row >= ROWS) return;

    const int* k = keys + (size_t)row * MAX_NNZ;
    const int* m = mask + (size_t)row * MAX_NNZ;

    float4 acc = make_float4(0.f, 0.f, 0.f, 0.f);
    int cnt = 0;

#pragma unroll
    for (int j = 0; j < MAX_NNZ; ++j) {
        int mj = m[j];                 // broadcast across the 16 lanes of this row
        if (mj) {
            ++cnt;
            const float4* rowp = (const float4*)(table + (size_t)k[j] * EMB);
            float4 v = rowp[e4];       // coalesced 256B across 16 lanes
            acc.x += v.x; acc.y += v.y; acc.z += v.z; acc.w += v.w;
        }
    }

    // mean combiner: divide by max(count, 1)
    float inv = 1.0f / (float)(cnt > 0 ? cnt : 1);
    acc.x *= inv; acc.y *= inv; acc.z *= inv; acc.w *= inv;

    ((float4*)(out + (size_t)row * EMB))[e4] = acc;
}

extern "C" void kernel_launch(void* const* d_in, const int* in_sizes, int n_in,
                              void* d_out, int out_size, void* d_ws, size_t ws_size,
                              hipStream_t stream) {
    const int*   keys  = (const int*)d_in[0];
    const int*   mask  = (const int*)d_in[1];
    const float* table = (const float*)d_in[2];
    float*       out   = (float*)d_out;

    const int threads_per_row = 16;
    const int block = 256;
    const long long total_threads = (long long)ROWS * threads_per_row;
    const int grid = (int)((total_threads + block - 1) / block);   // 6656 blocks

    emb_fwd_kernel<<<grid, block, 0, stream>>>(keys, mask, table, out);
}

// Round 2
// 342.810 us; speedup vs baseline: 1.0331x; 1.0331x over previous
//
#include <hip/hip_runtime.h>

#define BATCH   4096
#define SLOTS   26
#define MAX_NNZ 10
#define EMB     64
#define ROWS    (BATCH * SLOTS)   // 106,496 output rows

// One output row [EMB=64 floats] is handled by 16 lanes, each owning one
// float4. A 64-lane wave processes 4 rows concurrently.
//
// Branch-free: all MAX_NNZ gathers are issued unconditionally (keys are
// valid indices even when masked out), weighted by mask as 0.0/1.0. This
// keeps 10 independent global_load_dwordx4 in flight per thread instead of
// serializing them behind exec-mask branches (round-1 was latency-bound at
// ~570 GB/s effective).
__global__ __launch_bounds__(256) void emb_fwd_kernel(
    const int*   __restrict__ keys,   // [ROWS, MAX_NNZ]
    const int*   __restrict__ mask,   // [ROWS, MAX_NNZ] (0/1)
    const float* __restrict__ table,  // [VOCAB, EMB]
    float*       __restrict__ out)    // [ROWS, EMB]
{
    int tid = blockIdx.x * blockDim.x + threadIdx.x;
    int row = tid >> 4;        // 16 lanes per row
    int e4  = tid & 15;        // which float4 of the 64-float row
    if (row >= ROWS) return;

    const int* kp = keys + (size_t)row * MAX_NNZ;
    const int* mp = mask + (size_t)row * MAX_NNZ;

    // Load all keys + masks up front (independent loads, L1/L2-friendly:
    // 16 lanes of a row group hit the same cachelines).
    int kk[MAX_NNZ];
    int mm[MAX_NNZ];
#pragma unroll
    for (int j = 0; j < MAX_NNZ; ++j) kk[j] = kp[j];
#pragma unroll
    for (int j = 0; j < MAX_NNZ; ++j) mm[j] = mp[j];

    // Issue ALL gathers before consuming any — maximal memory-level
    // parallelism (10 outstanding 16B loads per thread).
    float4 v[MAX_NNZ];
#pragma unroll
    for (int j = 0; j < MAX_NNZ; ++j) {
        const float4* rowp = (const float4*)(table + (size_t)kk[j] * EMB);
        v[j] = rowp[e4];       // coalesced 256B across the 16 lanes
    }

    float4 acc = make_float4(0.f, 0.f, 0.f, 0.f);
    int cnt = 0;
#pragma unroll
    for (int j = 0; j < MAX_NNZ; ++j) {
        float w = (float)(mm[j] != 0);
        cnt += (mm[j] != 0);
        acc.x = fmaf(w, v[j].x, acc.x);
        acc.y = fmaf(w, v[j].y, acc.y);
        acc.z = fmaf(w, v[j].z, acc.z);
        acc.w = fmaf(w, v[j].w, acc.w);
    }

    // mean combiner: divide by max(count, 1)
    float inv = 1.0f / (float)(cnt > 0 ? cnt : 1);
    acc.x *= inv; acc.y *= inv; acc.z *= inv; acc.w *= inv;

    ((float4*)(out + (size_t)row * EMB))[e4] = acc;
}

extern "C" void kernel_launch(void* const* d_in, const int* in_sizes, int n_in,
                              void* d_out, int out_size, void* d_ws, size_t ws_size,
                              hipStream_t stream) {
    const int*   keys  = (const int*)d_in[0];
    const int*   mask  = (const int*)d_in[1];
    const float* table = (const float*)d_in[2];
    float*       out   = (float*)d_out;

    const int threads_per_row = 16;
    const int block = 256;
    const long long total_threads = (long long)ROWS * threads_per_row;
    const int grid = (int)((total_threads + block - 1) / block);   // 6656 blocks

    emb_fwd_kernel<<<grid, block, 0, stream>>>(keys, mask, table, out);
}

// Round 4
// 329.281 us; speedup vs baseline: 1.0756x; 1.0411x over previous
//
#include <hip/hip_runtime.h>

#define BATCH   4096
#define SLOTS   26
#define MAX_NNZ 10
#define EMB     64
#define ROWS    (BATCH * SLOTS)   // 106,496 output rows

typedef float floatx4 __attribute__((ext_vector_type(4)));

// One output row [EMB=64 floats] is handled by 16 lanes, each owning one
// float4. A 64-lane wave processes 4 rows concurrently.
//
// Branch-free + masked-to-dummy: all MAX_NNZ gathers are issued
// unconditionally for MLP, but masked-out entries redirect to table row 0
// (v_cndmask on the index — no divergence, the 16 lanes of a row share the
// mask). Row 0 stays L1-resident, so masked gathers cost ~nothing and the
// unique-row HBM fetch drops ~35-40% vs gathering real masked rows.
__global__ __launch_bounds__(256) void emb_fwd_kernel(
    const int*   __restrict__ keys,   // [ROWS, MAX_NNZ]
    const int*   __restrict__ mask,   // [ROWS, MAX_NNZ] (0/1)
    const float* __restrict__ table,  // [VOCAB, EMB]
    float*       __restrict__ out)    // [ROWS, EMB]
{
    int tid = blockIdx.x * blockDim.x + threadIdx.x;
    int row = tid >> 4;        // 16 lanes per row
    int e4  = tid & 15;        // which float4 of the 64-float row
    if (row >= ROWS) return;

    const int* kp = keys + (size_t)row * MAX_NNZ;
    const int* mp = mask + (size_t)row * MAX_NNZ;

    int kk[MAX_NNZ];
    int mm[MAX_NNZ];
#pragma unroll
    for (int j = 0; j < MAX_NNZ; ++j) kk[j] = kp[j];
#pragma unroll
    for (int j = 0; j < MAX_NNZ; ++j) mm[j] = mp[j];

    // Redirect masked-out gathers to row 0 (hot in L1). Branch-free.
#pragma unroll
    for (int j = 0; j < MAX_NNZ; ++j) {
        kk[j] = mm[j] ? kk[j] : 0;
    }

    // Issue ALL gathers before consuming any — 10 outstanding 16B loads
    // per thread.
    floatx4 v[MAX_NNZ];
#pragma unroll
    for (int j = 0; j < MAX_NNZ; ++j) {
        const floatx4* rowp = (const floatx4*)(table + (size_t)kk[j] * EMB);
        v[j] = rowp[e4];       // coalesced 256B across the 16 lanes
    }

    floatx4 acc = (floatx4){0.f, 0.f, 0.f, 0.f};
    int cnt = 0;
#pragma unroll
    for (int j = 0; j < MAX_NNZ; ++j) {
        float w = (float)(mm[j] != 0);
        cnt += (mm[j] != 0);
        acc += w * v[j];
    }

    // mean combiner: divide by max(count, 1)
    float inv = 1.0f / (float)(cnt > 0 ? cnt : 1);
    acc *= inv;

    // Streaming store — output has no reuse; keep L2/L3 for the table.
    floatx4* op = (floatx4*)(out + (size_t)row * EMB) + e4;
    __builtin_nontemporal_store(acc, op);
}

extern "C" void kernel_launch(void* const* d_in, const int* in_sizes, int n_in,
                              void* d_out, int out_size, void* d_ws, size_t ws_size,
                              hipStream_t stream) {
    const int*   keys  = (const int*)d_in[0];
    const int*   mask  = (const int*)d_in[1];
    const float* table = (const float*)d_in[2];
    float*       out   = (float*)d_out;

    const int threads_per_row = 16;
    const int block = 256;
    const long long total_threads = (long long)ROWS * threads_per_row;
    const int grid = (int)((total_threads + block - 1) / block);   // 6656 blocks

    emb_fwd_kernel<<<grid, block, 0, stream>>>(keys, mask, table, out);
}